// Round 2
// baseline (2228.826 us; speedup 1.0000x reference)
//
#include <hip/hip_runtime.h>
#include <math.h>

#define LOG2E 1.4426950408889634f
#define LN2   0.6931471805599453f

typedef short    short8  __attribute__((ext_vector_type(8)));
typedef float    floatx4 __attribute__((ext_vector_type(4)));
typedef _Float16 half8   __attribute__((ext_vector_type(8)));

__constant__ int c_pi[28] = {0,0,0,0,0,0,0,1,1,1,1,1,1,2,2,2,2,2,3,3,3,3,4,4,4,5,5,6};
__constant__ int c_pj[28] = {1,2,3,4,5,6,7,2,3,4,5,6,7,3,4,5,6,7,4,5,6,7,5,6,7,6,7,7};

// ---------------- static device storage ----------------
__device__ unsigned short g_cellsL[16*256*256];   // bf16 bits, gathered local cells
__device__ unsigned short g_cellsG[8*512*256];    // bf16 bits, gathered global cells
__device__ float g_x2L[16*256];
__device__ float g_x2G[8*512];
__device__ int   g_idxL[16*256];
__device__ int   g_idxG[8*512];
// fp16 cost matrices, NO explicit transposes (g-updates are column passes).
// Local: [0,56)=Cxy pairs, [56,72)=Cxx. 9.4 MB
__device__ _Float16 g_CL[72*256*256];
// Global: [0,28)=Cxy pairs, [28,36)=Cxx. 18.9 MB  (total 28.3 MB -> fits agg. L2)
__device__ _Float16 g_CG[36*512*512];
__device__ float g_fL[2][56*256];
__device__ float g_gL[2][56*256];
__device__ float g_pxL[2][16*256];
__device__ float g_fG[2][28*512];
__device__ float g_gG[2][28*512];
__device__ float g_pxG[2][8*512];

// ---------------- helpers ----------------
__device__ __forceinline__ unsigned short f2bf(float f) {
    unsigned u = __float_as_uint(f);
    u += 0x7fffu + ((u >> 16) & 1u);          // RNE; inputs are finite
    return (unsigned short)(u >> 16);
}

// ---------------- index lists: first-m matches in order (ballot scan) -------
__global__ void k_index(const int* __restrict__ labels, const int* __restrict__ subg) {
    int b = blockIdx.x, lane = threadIdx.x;   // 24 blocks x 64 threads
    int want_l, want_s, cap; int* out;
    if (b < 16) { want_l = b >> 3; want_s = b & 7; cap = 256; out = g_idxL + b*256; }
    else        { want_l = -1;     want_s = b - 16; cap = 512; out = g_idxG + (b-16)*512; }
    int cnt = 0;
    for (int base = 0; base < 4096; base += 64) {
        int i = base + lane;
        bool m = (subg[i] == want_s) && (want_l < 0 || labels[i] == want_l);
        unsigned long long mask = __ballot(m);
        int pos = cnt + __popcll(mask & ((1ull << lane) - 1ull));
        if (m && pos < cap) out[pos] = i;
        cnt += __popcll(mask);
    }
}

// ---------------- gather rows -> bf16 cells + fp32 sq-norms -----------------
__global__ void k_gather(const float* __restrict__ feat) {
    int wv = blockIdx.x*4 + (threadIdx.x >> 6);   // 8192 waves, one row each
    int lane = threadIdx.x & 63;
    const float* src; unsigned short* dst; float* x2out;
    if (wv < 4096) {
        int c = wv >> 8, row = wv & 255;
        src = feat + (size_t)g_idxL[c*256+row]*256;
        dst = g_cellsL + (size_t)(c*256+row)*256;
        x2out = g_x2L + c*256 + row;
    } else {
        int v = wv - 4096; int c = v >> 9, row = v & 511;
        src = feat + (size_t)g_idxG[c*512+row]*256;
        dst = g_cellsG + (size_t)(c*512+row)*256;
        x2out = g_x2G + c*512 + row;
    }
    floatx4 v4 = *(const floatx4*)(src + lane*4);
    float s = v4[0]*v4[0] + v4[1]*v4[1] + v4[2]*v4[2] + v4[3]*v4[3];
    unsigned lo = (unsigned)f2bf(v4[0]) | ((unsigned)f2bf(v4[1]) << 16);
    unsigned hi = (unsigned)f2bf(v4[2]) | ((unsigned)f2bf(v4[3]) << 16);
    unsigned* d32 = (unsigned*)dst;
    d32[lane*2] = lo; d32[lane*2+1] = hi;
    for (int o = 32; o; o >>= 1) s += __shfl_xor(s, o);
    if (lane == 0) *x2out = s;
}

// ---------------- cost matrices via bf16 MFMA (wave = one 16x16 tile) -------
// C_ij = 0.5*max(x2_i + y2_j - 2*x.y, 0), stored fp16. No transpose matrices.
__global__ void k_gemm() {
    int job = blockIdx.x*4 + (threadIdx.x >> 6);
    int lane = threadIdx.x & 63;
    const unsigned short *A, *B; _Float16* Cout; const float *x2a, *x2b;
    int m, ti, tj;
    if (job < 18432) {                      // local: 72 matrices x 256 tiles
        int mm = job >> 8, t = job & 255; ti = t >> 4; tj = t & 15; m = 256;
        int ca, cb;
        if (mm < 56) { int lbl = mm/28, q = mm%28; ca = lbl*8 + c_pi[q]; cb = lbl*8 + c_pj[q]; }
        else         { int c = mm-56; ca = cb = c; }
        A = g_cellsL + (size_t)ca*65536; B = g_cellsL + (size_t)cb*65536;
        x2a = g_x2L + ca*256; x2b = g_x2L + cb*256;
        Cout = g_CL + (size_t)mm*65536;
    } else {                                // global: 36 matrices x 1024 tiles
        int jj = job - 18432; int mm = jj >> 10, t = jj & 1023; ti = t >> 5; tj = t & 31; m = 512;
        int ca, cb;
        if (mm < 28) { ca = c_pi[mm]; cb = c_pj[mm]; }
        else         { ca = cb = mm-28; }
        A = g_cellsG + (size_t)ca*131072; B = g_cellsG + (size_t)cb*131072;
        x2a = g_x2G + ca*512; x2b = g_x2G + cb*512;
        Cout = g_CG + (size_t)mm*262144;
    }
    int r = lane & 15, quad = lane >> 4;
    const unsigned short* Ap = A + (size_t)(ti*16 + r)*256 + quad*8;
    const unsigned short* Bp = B + (size_t)(tj*16 + r)*256 + quad*8;
    floatx4 acc = {0.f, 0.f, 0.f, 0.f};
    #pragma unroll
    for (int k = 0; k < 256; k += 32) {
        short8 av = *(const short8*)(Ap + k);
        short8 bv = *(const short8*)(Bp + k);
        acc = __builtin_amdgcn_mfma_f32_16x16x32_bf16(av, bv, acc, 0, 0, 0);
    }
    int jc = tj*16 + r;                     // D: col = lane&15, row = quad*4 + reg
    float y2 = x2b[jc];
    #pragma unroll
    for (int rr = 0; rr < 4; rr++) {
        int ir = ti*16 + quad*4 + rr;
        float v = x2a[ir] + y2 - 2.f*acc[rr];
        Cout[(size_t)ir*m + jc] = (_Float16)(0.5f*fmaxf(v, 0.f));
    }
}

// ---------------- zero the parity-0 potential buffers -----------------------
__global__ void k_init() {
    int t = blockIdx.x*256 + threadIdx.x;   // 65536 threads
    if      (t < 14336) g_fL[0][t] = 0.f;
    else if (t < 28672) g_gL[0][t-14336] = 0.f;
    else if (t < 32768) g_pxL[0][t-28672] = 0.f;
    else if (t < 47104) g_fG[0][t-32768] = 0.f;
    else if (t < 61440) g_gG[0][t-47104] = 0.f;
    else                g_pxG[0][t-61440] = 0.f;
}

// ---------------- row softmin pass, fully register-resident -----------------
// ft_i = -eps*LSE_j(h_j - C_ij/eps).
// M=256: half-wave per row, 16 rows/wave, stripe = 64 rows.
// M=512: full wave per row, 8 rows/wave, stripe = 32 rows.
template<int M>
__device__ __forceinline__ void sm_pass(const _Float16* __restrict__ C,
    const float* __restrict__ hsrc, const float* __restrict__ fold,
    float* __restrict__ fout, int r0, float eps, float inv_eps, float loga,
    int hard, int fin)
{
    const int W = (M == 256) ? 16 : 32;     // shfl butterfly start
    int tid = threadIdx.x, lane = tid & 63, w = tid >> 6;
    int co = (M == 256) ? (lane & 31) : lane;
    float h[8];
    floatx4 h0 = *(const floatx4*)(hsrc + co*8);
    floatx4 h1 = *(const floatx4*)(hsrc + co*8 + 4);
    #pragma unroll
    for (int k = 0; k < 4; k++) { h[k] = loga + h0[k]*inv_eps; h[4+k] = loga + h1[k]*inv_eps; }
    int rbase = (M == 256) ? (r0 + w*16) : (r0 + w*8);
    int rowst = (M == 256) ? 2 : 1;
    int radd  = (M == 256) ? (lane >> 5) : 0;
    bool wr   = (M == 256) ? ((lane & 31) == 0) : (lane == 0);

    const _Float16* cp = C + (size_t)(rbase + radd)*M + co*8;
    half8 cv = *(const half8*)cp;           // 2-stage pipeline: prefetch next row
    #pragma unroll
    for (int s = 0; s < 8; s++) {
        half8 cvn = cv;
        if (s < 7) cvn = *(const half8*)(cp + (size_t)rowst*M);
        float tv[8]; float mx = -3.4e38f;
        #pragma unroll
        for (int k = 0; k < 8; k++) {
            float t = h[k] - (float)cv[k]*inv_eps;
            tv[k] = t; mx = fmaxf(mx, t);
        }
        #pragma unroll
        for (int o = W; o; o >>= 1) mx = fmaxf(mx, __shfl_xor(mx, o));
        float ft;
        if (!hard) {
            float sum = 0.f;
            #pragma unroll
            for (int k = 0; k < 8; k++) sum += exp2f((tv[k] - mx)*LOG2E);
            #pragma unroll
            for (int o = W; o; o >>= 1) sum += __shfl_xor(sum, o);
            ft = -eps*(mx + LN2*__log2f(sum));
        } else {
            ft = -eps*mx;                   // |err| <= eps*ln(M), negligible for eps<1e-5
        }
        if (wr) {
            int row = rbase + rowst*s + radd;
            fout[row] = fin ? ft : 0.5f*(fold[row] + ft);
        }
        cv = cvn; cp += (size_t)rowst*M;
    }
}

// ---------------- column softmin pass (replaces materialized transposes) ----
// gt_j = -eps*LSE_i(loga + f_i/eps - C_ij/eps), base-2 log domain.
// Block covers 64 columns [c0,c0+64) over ALL M rows; lane owns 8 columns'
// online (max,sum); 32 rows in flight per step (8 row-groups x 4 waves).
template<int M>
__device__ __forceinline__ void sm_col(const _Float16* __restrict__ C,
    const float* __restrict__ frow, const float* __restrict__ gold,
    float* __restrict__ gout, int c0, float eps, float inv_eps, float loga,
    int hard, int fin)
{
    int tid = threadIdx.x, lane = tid & 63, w = tid >> 6;
    const float i2  = inv_eps * LOG2E;
    const float lg2 = loga * LOG2E;
    int colg = lane & 7;                    // column-octet within the 64
    int rsub = (lane >> 3) + w*8;           // 0..31: row within step-group
    const int STEPS = M/32;
    float m2[8], ss[8];
    #pragma unroll
    for (int k = 0; k < 8; k++) { m2[k] = -3.4e38f; ss[k] = 0.f; }
    const _Float16* cp = C + (size_t)rsub*M + c0 + colg*8;
    half8 cv = *(const half8*)cp;           // 2-stage pipeline
    float fr = frow[rsub];
    #pragma unroll
    for (int s2 = 0; s2 < STEPS; s2++) {
        half8 cvn = cv; float frn = fr;
        if (s2 < STEPS-1) { cvn = *(const half8*)(cp + (size_t)32*M); frn = frow[rsub + 32*(s2+1)]; }
        float a2 = lg2 + fr * i2;
        if (!hard) {
            #pragma unroll
            for (int k = 0; k < 8; k++) {
                float u  = a2 - (float)cv[k]*i2;
                float mn = fmaxf(m2[k], u);
                ss[k] = ss[k]*exp2f(m2[k]-mn) + exp2f(u-mn);
                m2[k] = mn;
            }
        } else {
            #pragma unroll
            for (int k = 0; k < 8; k++) {
                float u = a2 - (float)cv[k]*i2;
                m2[k] = fmaxf(m2[k], u);
            }
        }
        cv = cvn; fr = frn; cp += (size_t)32*M;
    }
    // combine lanes sharing the same column-octet (xor 8,16,32)
    #pragma unroll
    for (int o = 8; o < 64; o <<= 1) {
        #pragma unroll
        for (int k = 0; k < 8; k++) {
            float mo = __shfl_xor(m2[k], o);
            float so = __shfl_xor(ss[k], o);
            float mn = fmaxf(m2[k], mo);
            if (!hard) ss[k] = ss[k]*exp2f(m2[k]-mn) + so*exp2f(mo-mn);
            m2[k] = mn;
        }
    }
    __shared__ float smm[4][64], sms[4][64];
    if (lane < 8) {
        #pragma unroll
        for (int k = 0; k < 8; k++) { smm[w][lane*8+k] = m2[k]; sms[w][lane*8+k] = ss[k]; }
    }
    __syncthreads();
    if (tid < 64) {
        float m = smm[0][tid], s = sms[0][tid];
        #pragma unroll
        for (int ww = 1; ww < 4; ww++) {
            float mo = smm[ww][tid], so = sms[ww][tid];
            float mn = fmaxf(m, mo);
            if (!hard) s = s*exp2f(m-mn) + so*exp2f(mo-mn);
            m = mn;
        }
        float gt = hard ? (-eps*LN2*m) : (-eps*LN2*(m + __log2f(s)));
        int c = c0 + tid;
        gout[c] = fin ? gt : 0.5f*(gold[c] + gt);
    }
}

// ---------------- one eps-scaling iteration, XCD-pinned ---------------------
// Grid = 8 x 176 blocks; XCD(b) = b&7 (round-robin heuristic), slot s = b>>3.
// Each matrix is statically assigned to one XCD so its row-jobs AND col-jobs
// share the same per-XCD L2 (<=3.6 MB/XCD working set, fits 4 MB L2).
//   s <  56 : local pair p = (s>>3)*8+x ; j=s&7 : j<4 row stripe, else col blk
//   s <  64 : local Cxx  c = ((s-56)>>2)*8+x ; stripe (s-56)&3
//   else    : globals; gp = (x<4)?4:3 pairs on this XCD, 24 jobs each
//             (16 row stripes + 8 col blocks), then 16 Cxx stripes (cell x).
__global__ void k_iter(float eps, float inv_eps, int par, int hard, int fin) {
    const float LGA = -5.545177444479562f;  // -ln 256
    const float LGG = -6.238324625039508f;  // -ln 512
    int b = blockIdx.x;
    int x = b & 7, s = b >> 3;
    int po = par, pn = par ^ 1;
    if (s < 56) {
        int q = s >> 3, j = s & 7, p = q*8 + x;
        const _Float16* C = g_CL + (size_t)p*65536;
        if (j < 4)
            sm_pass<256>(C, g_gL[po]+p*256, g_fL[po]+p*256, g_fL[pn]+p*256,
                         j*64, eps, inv_eps, LGA, hard, fin);
        else
            sm_col<256>(C, g_fL[po]+p*256, g_gL[po]+p*256, g_gL[pn]+p*256,
                        (j-4)*64, eps, inv_eps, LGA, hard, fin);
    } else if (s < 64) {
        int t = s - 56; int c = (t >> 2)*8 + x;
        const _Float16* C = g_CL + (size_t)(56+c)*65536;
        const float* h = g_pxL[po]+c*256;
        sm_pass<256>(C, h, h, g_pxL[pn]+c*256, (t&3)*64, eps, inv_eps, LGA, hard, fin);
    } else {
        int gp = (x < 4) ? 4 : 3;
        int t = s - 64;
        if (t < 24*gp) {
            int q = t/24, j = t%24, p = q*8 + x;
            const _Float16* C = g_CG + (size_t)p*262144;
            if (j < 16)
                sm_pass<512>(C, g_gG[po]+p*512, g_fG[po]+p*512, g_fG[pn]+p*512,
                             j*32, eps, inv_eps, LGG, hard, fin);
            else
                sm_col<512>(C, g_fG[po]+p*512, g_gG[po]+p*512, g_gG[pn]+p*512,
                            (j-16)*64, eps, inv_eps, LGG, hard, fin);
        } else {
            t -= 24*gp;
            if (t < 16) {
                const _Float16* C = g_CG + (size_t)(28+x)*262144;
                const float* h = g_pxG[po]+x*512;
                sm_pass<512>(C, h, h, g_pxG[pn]+x*512, t*32, eps, inv_eps, LGG, hard, fin);
            }
            // else: idle slot (XCDs 4-7 have 24 fewer jobs)
        }
    }
}

// ---------------- final reduction to the scalar loss ------------------------
__global__ void k_combine(float* __restrict__ out) {
    __shared__ float red[4][4];
    int tid = threadIdx.x;                  // 256 threads
    float sfg_l = 0.f, spx_l = 0.f, sfg_g = 0.f, spx_g = 0.f;
    for (int i = tid; i < 14336; i += 256) sfg_l += g_fL[1][i] + g_gL[1][i];
    for (int i = tid; i < 4096;  i += 256) spx_l += g_pxL[1][i];
    for (int i = tid; i < 14336; i += 256) sfg_g += g_fG[1][i] + g_gG[1][i];
    for (int i = tid; i < 4096;  i += 256) spx_g += g_pxG[1][i];
    for (int o = 32; o; o >>= 1) {
        sfg_l += __shfl_xor(sfg_l, o); spx_l += __shfl_xor(spx_l, o);
        sfg_g += __shfl_xor(sfg_g, o); spx_g += __shfl_xor(spx_g, o);
    }
    int w = tid >> 6;
    if ((tid & 63) == 0) { red[0][w] = sfg_l; red[1][w] = spx_l; red[2][w] = sfg_g; red[3][w] = spx_g; }
    __syncthreads();
    if (tid == 0) {
        float SL = red[0][0]+red[0][1]+red[0][2]+red[0][3];
        float PL = red[1][0]+red[1][1]+red[1][2]+red[1][3];
        float SG = red[2][0]+red[2][1]+red[2][2]+red[2][3];
        float PG = red[3][0]+red[3][1]+red[3][2]+red[3][3];
        float local_l  = SL/14336.f - PL/2048.f;
        float global_l = SG/14336.f - PG/2048.f;
        out[0] = 1.0f*local_l + 0.5f*global_l;
    }
}

// ---------------- host launcher ---------------------------------------------
extern "C" void kernel_launch(void* const* d_in, const int* in_sizes, int n_in,
                              void* d_out, int out_size, void* d_ws, size_t ws_size,
                              hipStream_t stream) {
    (void)in_sizes; (void)n_in; (void)out_size; (void)d_ws; (void)ws_size;
    const float* feat  = (const float*)d_in[0];
    const int* labels  = (const int*)d_in[1];
    const int* subg    = (const int*)d_in[2];

    k_index <<<24,    64, 0, stream>>>(labels, subg);
    k_gather<<<2048, 256, 0, stream>>>(feat);
    k_gemm  <<<13824,256, 0, stream>>>();   // 55296 tiles (no transposes), 4/block
    k_init  <<<256,  256, 0, stream>>>();

    // eps schedule identical to reference (double, like numpy)
    double eps0 = 4.0*256.0, ratio = 0.9*0.9, target = 1e-4*1e-4;
    int n = (int)ceil(log(target/eps0)/log(ratio));    // 121 -> 122 iterations
    float ef = 1e-8f;
    for (int k = 0; k <= n; k++) {
        double e = eps0 * pow(ratio, (double)k);
        if (e < target) e = target;
        ef = (float)e;
        int hard = (ef < 1e-5f) ? 1 : 0;
        k_iter<<<1408, 256, 0, stream>>>(ef, (float)(1.0/(double)ef), k & 1, hard, 0);
    }
    // final extrapolation at eps_f (reads parity 0 carry, writes raw to parity 1)
    k_iter<<<1408, 256, 0, stream>>>(ef, (float)(1.0/(double)ef), 0, 1, 1);
    k_combine<<<1, 256, 0, stream>>>((float*)d_out);
}